// Round 7
// baseline (963.377 us; speedup 1.0000x reference)
//
#include <hip/hip_runtime.h>
#include <hip/hip_bf16.h>
#include <math.h>

#define N_NODES 50000
#define M_PAD   50048           // 782 blocks * 64 rows
#define E_EDGES 800000
#define IN_DIM  512
#define HDIM    128
#define CDIM    40
#define LAYERS  8
#define NB      196             // scan blocks: ceil(50000/256)

// column-blocked x layout: x_cb[slice 0..7][row 0..M_PAD)[c 0..15]
#define XIDX(s, row, c) (((size_t)(s) * M_PAD + (row)) * 16 + (c))

typedef __attribute__((ext_vector_type(8))) short short8;
typedef __attribute__((ext_vector_type(4))) short short4v;
typedef __attribute__((ext_vector_type(4))) float floatx4;
typedef unsigned short ushort_t;

__device__ inline float bf2f(unsigned short u) {
    return __uint_as_float(((unsigned)u) << 16);
}
__device__ inline unsigned short f2bf(float v) {
    __hip_bfloat16 b = __float2bfloat16(v);
    return *reinterpret_cast<unsigned short*>(&b);
}
__device__ inline unsigned pack2(float lo, float hi) {
    return (unsigned)f2bf(lo) | ((unsigned)f2bf(hi) << 16);
}

// ---------------- CSR build ----------------

__global__ void hist_kernel(const int* __restrict__ dst, int* __restrict__ cnt) {
    int i = blockIdx.x * blockDim.x + threadIdx.x;
    if (i < E_EDGES) atomicAdd(&cnt[dst[i]], 1);
}

__global__ void scanA(const int* __restrict__ cnt, int* __restrict__ bsum) {
    __shared__ int sm[256];
    int t = threadIdx.x, i = blockIdx.x * 256 + t;
    sm[t] = (i < N_NODES) ? cnt[i] : 0;
    __syncthreads();
    for (int d = 128; d > 0; d >>= 1) {
        if (t < d) sm[t] += sm[t + d];
        __syncthreads();
    }
    if (t == 0) bsum[blockIdx.x] = sm[0];
}

__global__ void scanB(const int* __restrict__ bsum, int* __restrict__ boff) {
    __shared__ int sm[256];
    int t = threadIdx.x;
    sm[t] = (t < NB) ? bsum[t] : 0;
    __syncthreads();
    for (int d = 1; d < 256; d <<= 1) {
        int v = (t >= d) ? sm[t - d] : 0;
        __syncthreads();
        sm[t] += v;
        __syncthreads();
    }
    if (t < NB) boff[t] = (t > 0) ? sm[t - 1] : 0;
}

__global__ void scanC(const int* __restrict__ cnt, const int* __restrict__ boff,
                      int* __restrict__ row_start, int* __restrict__ cursor) {
    __shared__ int sm[256];
    int t = threadIdx.x, i = blockIdx.x * 256 + t;
    int v = (i < N_NODES) ? cnt[i] : 0;
    sm[t] = v;
    __syncthreads();
    for (int d = 1; d < 256; d <<= 1) {
        int x = (t >= d) ? sm[t - d] : 0;
        __syncthreads();
        sm[t] += x;
        __syncthreads();
    }
    if (i < N_NODES) {
        int incl = boff[blockIdx.x] + sm[t];
        int excl = incl - v;
        row_start[i] = excl;
        cursor[i]    = excl;
        if (i == N_NODES - 1) row_start[N_NODES] = incl;
    }
}

__global__ void scatter_kernel(const int* __restrict__ ei, const float* __restrict__ normA,
                               int* __restrict__ cursor, int2* __restrict__ perm) {
    int i = blockIdx.x * blockDim.x + threadIdx.x;
    if (i >= E_EDGES) return;
    int d = ei[E_EDGES + i];
    int idx = atomicAdd(&cursor[d], 1);
    perm[idx] = make_int2(ei[i], __float_as_int(normA[i]));
}

// ---------------- weight prep: transpose + bf16 convert ----------------

__global__ void prep_weights(const float* __restrict__ W0, const float* __restrict__ convW,
                             const float* __restrict__ W1,
                             ushort_t* __restrict__ Wt0, ushort_t* __restrict__ WtL,
                             ushort_t* __restrict__ Wt1) {
    int i = blockIdx.x * blockDim.x + threadIdx.x;
    if (i < 128 * 512) {
        int n = i >> 9, k = i & 511;
        Wt0[i] = f2bf(W0[k * HDIM + n]);
        return;
    }
    int j = i - 128 * 512;
    if (j < 8 * 128 * 128) {
        int l = j >> 14, rem = j & 16383, n = rem >> 7, k = rem & 127;
        WtL[j] = f2bf(convW[l * 16384 + k * HDIM + n]);
        return;
    }
    int m = j - 8 * 128 * 128;
    if (m < 48 * 128) {
        int n = m >> 7, k = m & 127;
        Wt1[m] = (n < CDIM) ? f2bf(W1[k * CDIM + n]) : (ushort_t)0;
    }
}

// ---------------- fc0: x = relu(F @ W0 + b0) -> h0b, xab (col-blocked bf16) -----
// 512 thr / 8 waves, 64 rows x 128 cols. 16 float4/thread prefetch; a barrier
// between load loop and convert loop forces all 16 loads in flight at once.

#define AROW 520   // 512 + 8 pad (shorts)

__global__ __launch_bounds__(512)
void fc0_mfma(const float* __restrict__ F, const ushort_t* __restrict__ Wt0,
              const float* __restrict__ b0,
              ushort_t* __restrict__ h0b, ushort_t* __restrict__ xab) {
    __shared__ short sA[64][AROW];   // 66.5 KB
    int t = threadIdx.x;
    int wave = t >> 6, lane = t & 63;
    int quad = lane >> 4, l16 = lane & 15;
    int rg = wave >> 1, cg = wave & 1;
    int row0 = blockIdx.x * 64;

    float4 pf[16];
#pragma unroll
    for (int i = 0; i < 16; i++) {
        int idx = t * 4 + i * 2048;            // 0..32764
        int r = row0 + (idx >> 9);
        if (r > N_NODES - 1) r = N_NODES - 1;  // OOB guard (values unused)
        pf[i] = *(const float4*)(F + (size_t)r * IN_DIM + (idx & 511));
    }
    __syncthreads();   // forces all 16 loads issued before first use (64 VGPRs live)
#pragma unroll
    for (int i = 0; i < 16; i++) {
        int idx = t * 4 + i * 2048;
        short4v s;
        s[0] = (short)f2bf(pf[i].x); s[1] = (short)f2bf(pf[i].y);
        s[2] = (short)f2bf(pf[i].z); s[3] = (short)f2bf(pf[i].w);
        *(short4v*)&sA[idx >> 9][idx & 511] = s;
    }
    __syncthreads();

    floatx4 acc[4];
#pragma unroll
    for (int nt = 0; nt < 4; nt++) acc[nt] = (floatx4){0.f, 0.f, 0.f, 0.f};

#pragma unroll
    for (int kc = 0; kc < 4; kc++) {
#pragma unroll
        for (int ks = 0; ks < 4; ks++) {
            short8 a = *(const short8*)&sA[rg * 16 + l16][kc * 128 + ks * 32 + quad * 8];
#pragma unroll
            for (int nt = 0; nt < 4; nt++) {
                short8 b = *(const short8*)(Wt0 + (size_t)(cg * 64 + nt * 16 + l16) * IN_DIM +
                                            kc * 128 + ks * 32 + quad * 8);
                acc[nt] = __builtin_amdgcn_mfma_f32_16x16x32_bf16(a, b, acc[nt], 0, 0, 0);
            }
        }
    }
#pragma unroll
    for (int nt = 0; nt < 4; nt++) {
        int s = cg * 4 + nt;               // col slice
        float bias = b0[s * 16 + l16];
#pragma unroll
        for (int r = 0; r < 4; r++) {
            int row = row0 + rg * 16 + quad * 4 + r;
            float v = acc[nt][r] + bias;
            v = v > 0.f ? v : 0.f;
            ushort_t u = f2bf(v);
            h0b[XIDX(s, row, l16)] = u;
            xab[XIDX(s, row, l16)] = u;
        }
    }
}

// -------- spmm (col-blocked): sup = 0.9*(A x) + 0.1*h0 --------
// slice = blockIdx & 7 -> matches XCD round-robin; slice data = 1.6 MB, L2-resident.
// 256 thr = 4 waves; wave = 8 rows x 8 lanes; lane owns 2 cols (4B granule); 4-deep pipeline.

__global__ void spmm_cb(const int* __restrict__ row_start, const int2* __restrict__ perm,
                        const ushort_t* __restrict__ xcb, const ushort_t* __restrict__ h0cb,
                        ushort_t* __restrict__ supcb) {
    int slice = blockIdx.x & 7;
    int rb    = blockIdx.x >> 3;
    int t = threadIdx.x;
    int wave = t >> 6, lane = t & 63;
    int rg = lane >> 3;          // row within wave (0..7)
    int cl = lane & 7;           // col-pair (0..7)
    int row = rb * 32 + wave * 8 + rg;
    bool live = row < N_NODES;
    int e0 = 0, e1 = 0;
    if (live) { e0 = row_start[row]; e1 = row_start[row + 1]; }

    const ushort_t* xs = xcb + (size_t)slice * M_PAD * 16;
    float a0 = 0.f, a1 = 0.f;

    int2 m[4];
    unsigned v[4];
#pragma unroll
    for (int d = 0; d < 4; d++)
        m[d] = (e0 + d < e1) ? perm[e0 + d] : make_int2(0, 0);
#pragma unroll
    for (int d = 0; d < 4; d++)
        if (e0 + d < e1) v[d] = *(const unsigned*)(xs + (size_t)m[d].x * 16 + cl * 2);

    for (int e = e0; e < e1; e += 4) {
        int2 mn[4];
#pragma unroll
        for (int d = 0; d < 4; d++) {
            int en = e + 4 + d;
            mn[d] = (en < e1) ? perm[en] : make_int2(0, 0);
        }
#pragma unroll
        for (int d = 0; d < 4; d++) {
            if (e + d < e1) {
                float w = __int_as_float(m[d].y);
                a0 += w * __uint_as_float(v[d] << 16);
                a1 += w * __uint_as_float(v[d] & 0xFFFF0000u);
            }
        }
#pragma unroll
        for (int d = 0; d < 4; d++) {
            if (e + 4 + d < e1)
                v[d] = *(const unsigned*)(xs + (size_t)mn[d].x * 16 + cl * 2);
            m[d] = mn[d];
        }
    }
    if (live) {
        unsigned h = *(const unsigned*)(h0cb + XIDX(slice, row, cl * 2));
        float o0 = 0.9f * a0 + 0.1f * __uint_as_float(h << 16);
        float o1 = 0.9f * a1 + 0.1f * __uint_as_float(h & 0xFFFF0000u);
        *(unsigned*)(supcb + XIDX(slice, row, cl * 2)) = pack2(o0, o1);
    }
}

// ---- layer GEMM (col-blocked): x = relu(beta*(S@W) + (1-beta)*S) ----
// 256 thr / 4 waves, 64 rows; A-frags read directly from col-blocked sup (16B loads).

__global__ void layer_gemm_cb(const ushort_t* __restrict__ S, const ushort_t* __restrict__ Wt,
                              ushort_t* __restrict__ X, float beta) {
    int t = threadIdx.x;
    int wave = t >> 6, lane = t & 63;
    int quad = lane >> 4, l16 = lane & 15;
    int row0 = blockIdx.x * 64;
    int R0 = row0 + wave * 16;

    int arow = R0 + l16;
    short8 afrag[4];
#pragma unroll
    for (int ks = 0; ks < 4; ks++)
        afrag[ks] = *(const short8*)(S + XIDX(ks * 2 + (quad >> 1), arow, (quad & 1) * 8));

    floatx4 acc[8];
#pragma unroll
    for (int nt = 0; nt < 8; nt++) {
        const ushort_t* bp = Wt + (size_t)(nt * 16 + l16) * HDIM + quad * 8;
        floatx4 c = (floatx4){0.f, 0.f, 0.f, 0.f};
#pragma unroll
        for (int ks = 0; ks < 4; ks++) {
            short8 b = *(const short8*)(bp + ks * 32);
            c = __builtin_amdgcn_mfma_f32_16x16x32_bf16(afrag[ks], b, c, 0, 0, 0);
        }
        acc[nt] = c;
    }
    float g = 1.f - beta;
#pragma unroll
    for (int nt = 0; nt < 8; nt++) {
#pragma unroll
        for (int r = 0; r < 4; r++) {
            int row = R0 + quad * 4 + r;
            float s = bf2f(S[XIDX(nt, row, l16)]);
            float v = beta * acc[nt][r] + g * s;
            v = v > 0.f ? v : 0.f;
            X[XIDX(nt, row, l16)] = f2bf(v);
        }
    }
}

// ---------------- fc1: out = x @ W1 + b1 (fp32 out), col-blocked input ----------------

__global__ void fc1_mfma(const ushort_t* __restrict__ X, const ushort_t* __restrict__ Wt1,
                         const float* __restrict__ b1, float* __restrict__ out) {
    int wave = threadIdx.x >> 6;
    int lane = threadIdx.x & 63;
    int quad = lane >> 4, l16 = lane & 15;
    int row0 = blockIdx.x * 64 + wave * 16;

    int arow = row0 + l16; if (arow > N_NODES - 1) arow = N_NODES - 1;
    short8 afrag[4];
#pragma unroll
    for (int ks = 0; ks < 4; ks++)
        afrag[ks] = *(const short8*)(X + XIDX(ks * 2 + (quad >> 1), arow, (quad & 1) * 8));

    floatx4 acc[3];
#pragma unroll
    for (int nt = 0; nt < 3; nt++) {
        const ushort_t* bp = Wt1 + (size_t)(nt * 16 + l16) * HDIM + quad * 8;
        floatx4 c = (floatx4){0.f, 0.f, 0.f, 0.f};
#pragma unroll
        for (int ks = 0; ks < 4; ks++) {
            short8 b = *(const short8*)(bp + ks * 32);
            c = __builtin_amdgcn_mfma_f32_16x16x32_bf16(afrag[ks], b, c, 0, 0, 0);
        }
        acc[nt] = c;
    }
#pragma unroll
    for (int nt = 0; nt < 3; nt++) {
        int col = nt * 16 + l16;
        if (col < CDIM) {
            float bias = b1[col];
#pragma unroll
            for (int r = 0; r < 4; r++) {
                int row = row0 + quad * 4 + r;
                if (row < N_NODES)
                    out[(size_t)row * CDIM + col] = acc[nt][r] + bias;
            }
        }
    }
}

// ---------------- launch ----------------

extern "C" void kernel_launch(void* const* d_in, const int* in_sizes, int n_in,
                              void* d_out, int out_size, void* d_ws, size_t ws_size,
                              hipStream_t stream) {
    const float* F     = (const float*)d_in[0];
    const int*   ei    = (const int*)d_in[1];
    const float* normA = (const float*)d_in[2];
    const float* W0    = (const float*)d_in[3];
    const float* b0    = (const float*)d_in[4];
    const float* convW = (const float*)d_in[5];
    const float* W1    = (const float*)d_in[6];
    const float* b1    = (const float*)d_in[7];
    float*       out   = (float*)d_out;

    // workspace layout (bf16 trunk, col-blocked), 16B-aligned
    ushort_t* h0b  = (ushort_t*)d_ws;                     // 8*M_PAD*16
    ushort_t* xab  = h0b + (size_t)8 * M_PAD * 16;
    ushort_t* xbb  = xab + (size_t)8 * M_PAD * 16;        // sup
    ushort_t* Wt0  = xbb + (size_t)8 * M_PAD * 16;        // 128*512
    ushort_t* WtL  = Wt0 + 128 * 512;                     // 8*128*128
    ushort_t* Wt1  = WtL + 8 * 128 * 128;                 // 48*128
    int*   row_start = (int*)(Wt1 + 48 * 128);
    int*   cursor    = row_start + (N_NODES + 8);
    int*   cnt       = cursor + (N_NODES + 8);
    int*   bsum      = cnt + (N_NODES + 8);
    int*   boff      = bsum + 256;
    int2*  perm      = (int2*)(boff + 256);               // 8B-aligned

    // CSR build
    hipMemsetAsync(cnt, 0, N_NODES * sizeof(int), stream);
    hist_kernel<<<(E_EDGES + 255) / 256, 256, 0, stream>>>(ei + E_EDGES, cnt);
    scanA<<<NB, 256, 0, stream>>>(cnt, bsum);
    scanB<<<1, 256, 0, stream>>>(bsum, boff);
    scanC<<<NB, 256, 0, stream>>>(cnt, boff, row_start, cursor);
    scatter_kernel<<<(E_EDGES + 255) / 256, 256, 0, stream>>>(ei, normA, cursor, perm);
    prep_weights<<<(128 * 512 + 8 * 128 * 128 + 48 * 128 + 255) / 256, 256, 0, stream>>>(
        W0, convW, W1, Wt0, WtL, Wt1);

    fc0_mfma<<<M_PAD / 64, 512, 0, stream>>>(F, Wt0, b0, h0b, xab);

    for (int i = 0; i < LAYERS; i++) {
        float beta = logf(0.5f / (float)(i + 1) + 1.0f);
        spmm_cb<<<(M_PAD / 32) * 8, 256, 0, stream>>>(row_start, perm, xab, h0b, xbb);
        layer_gemm_cb<<<M_PAD / 64, 256, 0, stream>>>(
            xbb, WtL + (size_t)i * HDIM * HDIM, xab, beta);
    }

    fc1_mfma<<<M_PAD / 64, 256, 0, stream>>>(xab, Wt1, b1, out);
}